// Round 1
// baseline (961.529 us; speedup 1.0000x reference)
//
#include <hip/hip_runtime.h>

// ---------------- types ----------------
typedef __bf16 bf16x8 __attribute__((ext_vector_type(8)));
typedef float f32x4 __attribute__((ext_vector_type(4)));

// f32 -> bf16 round-to-nearest-even (bit-level, no hip_bf16 API dependency)
__device__ __forceinline__ unsigned short f2bf(float f) {
    unsigned int u = __builtin_bit_cast(unsigned int, f);
    u += 0x7FFFu + ((u >> 16) & 1u);
    return (unsigned short)(u >> 16);
}

// ---------------- weight f32 -> bf16 conversion ----------------
__global__ void cvt_kernel(const float* __restrict__ in,
                           unsigned short* __restrict__ out, long n4) {
    long i = (long)blockIdx.x * blockDim.x + threadIdx.x;
    long stride = (long)gridDim.x * blockDim.x;
    for (; i < n4; i += stride) {
        float4 v = ((const float4*)in)[i];
        ushort4 o;
        o.x = f2bf(v.x); o.y = f2bf(v.y); o.z = f2bf(v.z); o.w = f2bf(v.w);
        ((ushort4*)out)[i] = o;
    }
}

// ---------------- fused 2-token attention -> h0 (bf16) ----------------
// one wave per row; D=1024. h[row][0:1024] = attn-weighted token0,
// h[row][1024:2048] = token1.
__global__ __launch_bounds__(256) void attn_kernel(
    const float* __restrict__ x1, const float* __restrict__ x2,
    unsigned short* __restrict__ h) {
    const int D = 1024;
    const int lane = threadIdx.x & 63;
    const int wave = threadIdx.x >> 6;
    const long row = (long)blockIdx.x * 4 + wave;
    const float4* p1 = (const float4*)(x1 + row * D);
    const float4* p2 = (const float4*)(x2 + row * D);
    float4 v1[4], v2[4];
    float s11 = 0.f, s12 = 0.f, s22 = 0.f;
#pragma unroll
    for (int j = 0; j < 4; ++j) {
        v1[j] = p1[lane + 64 * j];
        v2[j] = p2[lane + 64 * j];
        s11 += v1[j].x * v1[j].x + v1[j].y * v1[j].y + v1[j].z * v1[j].z + v1[j].w * v1[j].w;
        s12 += v1[j].x * v2[j].x + v1[j].y * v2[j].y + v1[j].z * v2[j].z + v1[j].w * v2[j].w;
        s22 += v2[j].x * v2[j].x + v2[j].y * v2[j].y + v2[j].z * v2[j].z + v2[j].w * v2[j].w;
    }
#pragma unroll
    for (int off = 1; off < 64; off <<= 1) {
        s11 += __shfl_xor(s11, off);
        s12 += __shfl_xor(s12, off);
        s22 += __shfl_xor(s22, off);
    }
    // softmax over 2 logits == sigmoid of logit difference
    const float a00 = 1.f / (1.f + expf((s12 - s11) * (1.f / 32.f)));
    const float a10 = 1.f / (1.f + expf((s22 - s12) * (1.f / 32.f)));
    const float a01 = 1.f - a00, a11 = 1.f - a10;
    unsigned short* h0 = h + row * 2048;
#pragma unroll
    for (int j = 0; j < 4; ++j) {
        const int f = lane + 64 * j;
        ushort4 o0, o1;
        o0.x = f2bf(a00 * v1[j].x + a01 * v2[j].x);
        o0.y = f2bf(a00 * v1[j].y + a01 * v2[j].y);
        o0.z = f2bf(a00 * v1[j].z + a01 * v2[j].z);
        o0.w = f2bf(a00 * v1[j].w + a01 * v2[j].w);
        o1.x = f2bf(a10 * v1[j].x + a11 * v2[j].x);
        o1.y = f2bf(a10 * v1[j].y + a11 * v2[j].y);
        o1.z = f2bf(a10 * v1[j].z + a11 * v2[j].z);
        o1.w = f2bf(a10 * v1[j].w + a11 * v2[j].w);
        ((ushort4*)(h0))[f] = o0;
        ((ushort4*)(h0 + 1024))[f] = o1;
    }
}

// ---------------- GEMM: C[M,N] = act(A[M,K] * Bw[N,K]^T + bias) ----------------
// m97-structure: 128x128 tile, BK=32, 256 thr = 4 waves (2x2), 16x16x32 bf16 MFMA,
// global_load_lds width-16 staging (linear LDS dest, per-lane global src).
template <bool RELU, typename OT>
__global__ __launch_bounds__(256) void gemm_bt(
    const unsigned short* __restrict__ A,   // [M,K] bf16
    const unsigned short* __restrict__ Bw,  // [N,K] bf16
    const float* __restrict__ bias,         // [N]
    OT* __restrict__ C,                     // [M,N]
    int N, int K) {
    __shared__ unsigned short sA[128 * 32];
    __shared__ unsigned short sB[128 * 32];
    const int lane = threadIdx.x & 63;
    const int wave = threadIdx.x >> 6;
    const int wm = wave >> 1, wn = wave & 1;
    const long m0 = (long)blockIdx.x * 128;
    const long n0 = (long)blockIdx.y * 128;
    const int fr = lane & 15, fq = lane >> 4;

    f32x4 acc[4][4] = {};

    // staging geometry: chunk c (0..7) = LDS bytes [c*1024, c*1024+1024),
    // covering tile rows c*16 + lane/4, k-elems (lane%4)*8 .. +8
    const int srow = lane >> 2;
    const int skk = (lane & 3) * 8;
    const unsigned short* gA = A + (m0 + srow) * K + skk;
    const unsigned short* gB = Bw + (n0 + srow) * K + skk;
    const int c0 = wave, c1 = wave + 4;

    for (int k0 = 0; k0 < K; k0 += 32) {
        __builtin_amdgcn_global_load_lds(
            (const __attribute__((address_space(1))) void*)(gA + (long)c0 * 16 * K + k0),
            (__attribute__((address_space(3))) void*)(sA + c0 * 512), 16, 0, 0);
        __builtin_amdgcn_global_load_lds(
            (const __attribute__((address_space(1))) void*)(gA + (long)c1 * 16 * K + k0),
            (__attribute__((address_space(3))) void*)(sA + c1 * 512), 16, 0, 0);
        __builtin_amdgcn_global_load_lds(
            (const __attribute__((address_space(1))) void*)(gB + (long)c0 * 16 * K + k0),
            (__attribute__((address_space(3))) void*)(sB + c0 * 512), 16, 0, 0);
        __builtin_amdgcn_global_load_lds(
            (const __attribute__((address_space(1))) void*)(gB + (long)c1 * 16 * K + k0),
            (__attribute__((address_space(3))) void*)(sB + c1 * 512), 16, 0, 0);
        __syncthreads();

        bf16x8 af[4], bfv[4];
#pragma unroll
        for (int m = 0; m < 4; ++m)
            af[m] = *(const bf16x8*)(sA + (wm * 64 + m * 16 + fr) * 32 + fq * 8);
#pragma unroll
        for (int n = 0; n < 4; ++n)
            bfv[n] = *(const bf16x8*)(sB + (wn * 64 + n * 16 + fr) * 32 + fq * 8);
#pragma unroll
        for (int m = 0; m < 4; ++m)
#pragma unroll
            for (int n = 0; n < 4; ++n)
                acc[m][n] = __builtin_amdgcn_mfma_f32_16x16x32_bf16(
                    af[m], bfv[n], acc[m][n], 0, 0, 0);
        __syncthreads();
    }

    // epilogue: C/D layout col = lane&15, row = (lane>>4)*4 + r
#pragma unroll
    for (int n = 0; n < 4; ++n) {
        const long col = n0 + wn * 64 + n * 16 + fr;
        const float bv = bias[col];
#pragma unroll
        for (int m = 0; m < 4; ++m) {
            const long row = m0 + wm * 64 + m * 16 + fq * 4;
#pragma unroll
            for (int r = 0; r < 4; ++r) {
                float v = acc[m][n][r] + bv;
                if (RELU) v = v > 0.f ? v : 0.f;
                if constexpr (sizeof(OT) == 2) {
                    C[(row + r) * N + col] = (OT)f2bf(v);
                } else {
                    C[(row + r) * N + col] = v;
                }
            }
        }
    }
}

// ---------------- launch ----------------
extern "C" void kernel_launch(void* const* d_in, const int* in_sizes, int n_in,
                              void* d_out, int out_size, void* d_ws, size_t ws_size,
                              hipStream_t stream) {
    const float* x1 = (const float*)d_in[0];
    const float* x2 = (const float*)d_in[1];
    const float* Ws = (const float*)d_in[2];   // [4,2048,2048]
    const float* bs = (const float*)d_in[3];   // [4,2048]
    const float* Wl = (const float*)d_in[4];   // [1024,2048]
    const float* bl = (const float*)d_in[5];   // [1024]
    float* out = (float*)d_out;                // [16384,1024]

    char* ws = (char*)d_ws;
    unsigned short* hA  = (unsigned short*)(ws);                  // 16384*2048 bf16 = 64 MiB
    unsigned short* hB  = (unsigned short*)(ws + (67108864L));    // 64 MiB
    unsigned short* Wbf = (unsigned short*)(ws + (134217728L));   // 4*2048*2048 bf16 = 32 MiB
    unsigned short* Wlb = (unsigned short*)(ws + (167772160L));   // 1024*2048 bf16 = 4 MiB

    // 1. weights -> bf16
    cvt_kernel<<<2048, 256, 0, stream>>>(Ws, Wbf, 4L * 2048 * 2048 / 4);
    cvt_kernel<<<512, 256, 0, stream>>>(Wl, Wlb, 1024L * 2048 / 4);

    // 2. attention -> h0
    attn_kernel<<<16384 / 4, 256, 0, stream>>>(x1, x2, hA);

    // 3. MLP: 4x relu GEMM (bf16 out, ping-pong) + final GEMM (f32 out)
    dim3 g1(16384 / 128, 2048 / 128);
    gemm_bt<true, unsigned short><<<g1, 256, 0, stream>>>(hA, Wbf + 0L * 2048 * 2048, bs + 0 * 2048, hB, 2048, 2048);
    gemm_bt<true, unsigned short><<<g1, 256, 0, stream>>>(hB, Wbf + 1L * 2048 * 2048, bs + 1 * 2048, hA, 2048, 2048);
    gemm_bt<true, unsigned short><<<g1, 256, 0, stream>>>(hA, Wbf + 2L * 2048 * 2048, bs + 2 * 2048, hB, 2048, 2048);
    gemm_bt<true, unsigned short><<<g1, 256, 0, stream>>>(hB, Wbf + 3L * 2048 * 2048, bs + 3 * 2048, hA, 2048, 2048);
    dim3 g2(16384 / 128, 1024 / 128);
    gemm_bt<false, float><<<g2, 256, 0, stream>>>(hA, Wlb, bl, out, 1024, 2048);
}

// Round 4
// 665.474 us; speedup vs baseline: 1.4449x; 1.4449x over previous
//
#include <hip/hip_runtime.h>

// ---------------- types ----------------
typedef __bf16 bf16x8 __attribute__((ext_vector_type(8)));
typedef float f32x4 __attribute__((ext_vector_type(4)));

__device__ __forceinline__ unsigned short f2bf(float f) {
    unsigned int u = __builtin_bit_cast(unsigned int, f);
    u += 0x7FFFu + ((u >> 16) & 1u);
    return (unsigned short)(u >> 16);
}

// ---------------- weight f32 -> bf16 conversion ----------------
__global__ void cvt_kernel(const float* __restrict__ in,
                           unsigned short* __restrict__ out, long n4) {
    long i = (long)blockIdx.x * blockDim.x + threadIdx.x;
    long stride = (long)gridDim.x * blockDim.x;
    for (; i < n4; i += stride) {
        float4 v = ((const float4*)in)[i];
        ushort4 o;
        o.x = f2bf(v.x); o.y = f2bf(v.y); o.z = f2bf(v.z); o.w = f2bf(v.w);
        ((ushort4*)out)[i] = o;
    }
}

// ---------------- fused 2-token attention -> h0 (bf16) ----------------
__global__ __launch_bounds__(256) void attn_kernel(
    const float* __restrict__ x1, const float* __restrict__ x2,
    unsigned short* __restrict__ h) {
    const int D = 1024;
    const int lane = threadIdx.x & 63;
    const int wave = threadIdx.x >> 6;
    const long row = (long)blockIdx.x * 4 + wave;
    const float4* p1 = (const float4*)(x1 + row * D);
    const float4* p2 = (const float4*)(x2 + row * D);
    float4 v1[4], v2[4];
    float s11 = 0.f, s12 = 0.f, s22 = 0.f;
#pragma unroll
    for (int j = 0; j < 4; ++j) {
        v1[j] = p1[lane + 64 * j];
        v2[j] = p2[lane + 64 * j];
        s11 += v1[j].x * v1[j].x + v1[j].y * v1[j].y + v1[j].z * v1[j].z + v1[j].w * v1[j].w;
        s12 += v1[j].x * v2[j].x + v1[j].y * v2[j].y + v1[j].z * v2[j].z + v1[j].w * v2[j].w;
        s22 += v2[j].x * v2[j].x + v2[j].y * v2[j].y + v2[j].z * v2[j].z + v2[j].w * v2[j].w;
    }
#pragma unroll
    for (int off = 1; off < 64; off <<= 1) {
        s11 += __shfl_xor(s11, off);
        s12 += __shfl_xor(s12, off);
        s22 += __shfl_xor(s22, off);
    }
    const float a00 = 1.f / (1.f + expf((s12 - s11) * (1.f / 32.f)));
    const float a10 = 1.f / (1.f + expf((s22 - s12) * (1.f / 32.f)));
    const float a01 = 1.f - a00, a11 = 1.f - a10;
    unsigned short* h0 = h + row * 2048;
#pragma unroll
    for (int j = 0; j < 4; ++j) {
        const int f = lane + 64 * j;
        ushort4 o0, o1;
        o0.x = f2bf(a00 * v1[j].x + a01 * v2[j].x);
        o0.y = f2bf(a00 * v1[j].y + a01 * v2[j].y);
        o0.z = f2bf(a00 * v1[j].z + a01 * v2[j].z);
        o0.w = f2bf(a00 * v1[j].w + a01 * v2[j].w);
        o1.x = f2bf(a10 * v1[j].x + a11 * v2[j].x);
        o1.y = f2bf(a10 * v1[j].y + a11 * v2[j].y);
        o1.z = f2bf(a10 * v1[j].z + a11 * v2[j].z);
        o1.w = f2bf(a10 * v1[j].w + a11 * v2[j].w);
        ((ushort4*)(h0))[f] = o0;
        ((ushort4*)(h0 + 1024))[f] = o1;
    }
}

// ---------------- 256x256 8-phase GEMM: C = act(A[M,K] * Bw[N,K]^T + bias) ----
// BM=BN=256, BK=64, 8 waves (2Mx4N), 128 KiB LDS = 2 K-tile dbuf.
// LDS chunk swizzle: slot = row*8 + (kc ^ (row&7)), 16B chunks; applied on
// BOTH the pre-swizzled global_load_lds source and the ds_read address.
#define BAR   __builtin_amdgcn_s_barrier()
#define LGKM0 asm volatile("s_waitcnt lgkmcnt(0)" ::: "memory")
#define PRIO1 __builtin_amdgcn_s_setprio(1)
#define PRIO0 __builtin_amdgcn_s_setprio(0)

#define MM8(mi0, A00, A01, mi1, A10, A11)                                                        \
  _Pragma("unroll") for (int n = 0; n < 4; ++n) {                                                \
    acc[mi0][n] = __builtin_amdgcn_mfma_f32_16x16x32_bf16(A00, Bf[n][0], acc[mi0][n], 0, 0, 0);  \
    acc[mi0][n] = __builtin_amdgcn_mfma_f32_16x16x32_bf16(A01, Bf[n][1], acc[mi0][n], 0, 0, 0);  \
    acc[mi1][n] = __builtin_amdgcn_mfma_f32_16x16x32_bf16(A10, Bf[n][0], acc[mi1][n], 0, 0, 0);  \
    acc[mi1][n] = __builtin_amdgcn_mfma_f32_16x16x32_bf16(A11, Bf[n][1], acc[mi1][n], 0, 0, 0);  \
  }

template <bool RELU, typename OT>
__global__ __launch_bounds__(512, 2) void gemm256(
    const unsigned short* __restrict__ A,   // [M,K] bf16
    const unsigned short* __restrict__ Bw,  // [N,K] bf16
    const float* __restrict__ bias,         // [N]
    OT* __restrict__ C,                     // [M,N]
    int N, int K) {
    __shared__ unsigned short lds[65536];   // 128 KiB: T0 [A 32K | B 32K], T1 same
    const int tid = threadIdx.x;
    const int lane = tid & 63, wave = tid >> 6;
    const int wm = wave >> 2, wn = wave & 3;
    const int fr = lane & 15, fq = lane >> 4;

    // XCD-swizzled 1D block id -> (bm, bn); M/256 == 64 always here.
    const int cpx = (int)gridDim.x >> 3;
    const int swz = ((int)blockIdx.x & 7) * cpx + ((int)blockIdx.x >> 3);
    const int bm = swz & 63;
    const int bn = swz >> 6;
    const long m0 = (long)bm * 256, n0 = (long)bn * 256;

    // LDS read bases (byte offsets). kk=1 address = kk=0 address ^ 64.
    const int x0 = fq ^ (fr & 7);
    const int lane_base = fr * 128 + x0 * 16;
    const int aBase = wm * 16384 + lane_base;
    const int bBase = 32768 + (wn >> 1) * 16384 + (wn & 1) * 8192 + lane_base;
    const char* ldsc = (const char*)lds;

    // staging: per-lane pre-swizzled global source offset (same for A and B)
    const int l3 = lane >> 3, l7 = lane & 7;
    const long rowb = (long)K * 2;
    const long lane_src = (long)l3 * rowb + ((l7 ^ l3) << 4);
    const char* Abl = (const char*)A + m0 * rowb + lane_src;
    const char* Bbl = (const char*)Bw + n0 * rowb + lane_src;

    auto stage = [&](const char* mb, int matOff, int hf, int kt, int T) {
#pragma unroll
        for (int r = 0; r < 2; ++r) {
            const int W = r * 8 + wave;
            const char* src = mb + (long)(hf * 128 + W * 8) * rowb + kt * 128;
            __builtin_amdgcn_global_load_lds(
                (const __attribute__((address_space(1))) void*)src,
                (__attribute__((address_space(3))) void*)((char*)lds +
                    (T * 65536 + matOff + hf * 16384 + W * 1024)),
                16, 0, 0);
        }
    };

    f32x4 acc[8][4] = {};
    bf16x8 Bf[4][2], A0f[2][2], AL[6][2];

    auto readP1 = [&](int boff) {   // B all + A m0,1
#pragma unroll
        for (int n = 0; n < 4; ++n) {
            Bf[n][0] = *(const bf16x8*)(ldsc + boff + bBase + n * 2048);
            Bf[n][1] = *(const bf16x8*)(ldsc + boff + (bBase ^ 64) + n * 2048);
        }
#pragma unroll
        for (int m = 0; m < 2; ++m) {
            A0f[m][0] = *(const bf16x8*)(ldsc + boff + aBase + m * 2048);
            A0f[m][1] = *(const bf16x8*)(ldsc + boff + (aBase ^ 64) + m * 2048);
        }
    };
    auto readP2 = [&](int boff) {   // A m2..7
#pragma unroll
        for (int m = 0; m < 6; ++m) {
            AL[m][0] = *(const bf16x8*)(ldsc + boff + aBase + (m + 2) * 2048);
            AL[m][1] = *(const bf16x8*)(ldsc + boff + (aBase ^ 64) + (m + 2) * 2048);
        }
    };

    // ---- prologue: tile0 (all 4 halves) -> T0; tile1 A halves -> T1 ----
    stage(Abl, 0,     0, 0, 0); stage(Abl, 0,     1, 0, 0);
    stage(Bbl, 32768, 0, 0, 0); stage(Bbl, 32768, 1, 0, 0);
    stage(Abl, 0,     0, 1, 1); stage(Abl, 0,     1, 1, 1);
    asm volatile("s_waitcnt vmcnt(4)" ::: "memory");
    BAR;

    const int NT = K >> 6;       // 32 K-tiles
    const int NIT = NT >> 1;     // 16 iterations, 2 K-tiles each
    for (int i = 0; i < NIT; ++i) {
        const int t1 = 2 * i + 1, t2 = t1 + 1, t3 = t1 + 2;
        const bool g = (i + 1 < NIT);

        // P1: read B(t0)+A01(t0) from T0; stage B0(t1)->T1
        readP1(0);
        stage(Bbl, 32768, 0, t1, 1);
        BAR; LGKM0; PRIO1;
        MM8(0, A0f[0][0], A0f[0][1], 1, A0f[1][0], A0f[1][1]);
        PRIO0; BAR;

        // P2: read A m2..7(t0); stage B1(t1)->T1
        readP2(0);
        stage(Bbl, 32768, 1, t1, 1);
        BAR; LGKM0; PRIO1;
        MM8(2, AL[0][0], AL[0][1], 3, AL[1][0], AL[1][1]);
        PRIO0; BAR;

        // P3: stage A0(t2)->T0 (T0 reads all done at P2)
        if (g) stage(Abl, 0, 0, t2, 0);
        BAR; PRIO1;
        MM8(4, AL[2][0], AL[2][1], 5, AL[3][0], AL[3][1]);
        PRIO0; BAR;

        // P4: stage A1(t2)->T0; counted vmcnt retires B(t1)
        if (g) stage(Abl, 0, 1, t2, 0);
        BAR; PRIO1;
        MM8(6, AL[4][0], AL[4][1], 7, AL[5][0], AL[5][1]);
        PRIO0;
        if (g) { asm volatile("s_waitcnt vmcnt(4)" ::: "memory"); }
        else   { asm volatile("s_waitcnt vmcnt(0)" ::: "memory"); }
        BAR;

        // P5: read B(t1)+A01(t1) from T1; stage B0(t2)->T0
        readP1(65536);
        if (g) stage(Bbl, 32768, 0, t2, 0);
        BAR; LGKM0; PRIO1;
        MM8(0, A0f[0][0], A0f[0][1], 1, A0f[1][0], A0f[1][1]);
        PRIO0; BAR;

        // P6: read A m2..7(t1); stage B1(t2)->T0
        readP2(65536);
        if (g) stage(Bbl, 32768, 1, t2, 0);
        BAR; LGKM0; PRIO1;
        MM8(2, AL[0][0], AL[0][1], 3, AL[1][0], AL[1][1]);
        PRIO0; BAR;

        // P7: stage A0(t3)->T1 (T1 reads done at P6)
        if (g) stage(Abl, 0, 0, t3, 1);
        BAR; PRIO1;
        MM8(4, AL[2][0], AL[2][1], 5, AL[3][0], AL[3][1]);
        PRIO0; BAR;

        // P8: stage A1(t3)->T1; counted vmcnt retires B(t2)
        if (g) stage(Abl, 0, 1, t3, 1);
        BAR; PRIO1;
        MM8(6, AL[4][0], AL[4][1], 7, AL[5][0], AL[5][1]);
        PRIO0;
        if (g) { asm volatile("s_waitcnt vmcnt(4)" ::: "memory"); }
        else   { asm volatile("s_waitcnt vmcnt(0)" ::: "memory"); }
        BAR;
    }

    // ---- epilogue: C/D layout col = lane&15, row = (lane>>4)*4 + r ----
    const long crow0 = m0 + wm * 128 + fq * 4;
    const long ccol0 = n0 + wn * 64 + fr;
#pragma unroll
    for (int n = 0; n < 4; ++n) {
        const float bv = bias[ccol0 + n * 16];
#pragma unroll
        for (int m = 0; m < 8; ++m) {
#pragma unroll
            for (int r = 0; r < 4; ++r) {
                float v = acc[m][n][r] + bv;
                if (RELU) v = v > 0.f ? v : 0.f;
                OT* p = C + (crow0 + m * 16 + r) * N + (ccol0 + n * 16);
                if constexpr (sizeof(OT) == 2) *p = (OT)f2bf(v);
                else *p = v;
            }
        }
    }
}

// ---------------- launch ----------------
extern "C" void kernel_launch(void* const* d_in, const int* in_sizes, int n_in,
                              void* d_out, int out_size, void* d_ws, size_t ws_size,
                              hipStream_t stream) {
    const float* x1 = (const float*)d_in[0];
    const float* x2 = (const float*)d_in[1];
    const float* Ws = (const float*)d_in[2];   // [4,2048,2048]
    const float* bs = (const float*)d_in[3];   // [4,2048]
    const float* Wl = (const float*)d_in[4];   // [1024,2048]
    const float* bl = (const float*)d_in[5];   // [1024]
    float* out = (float*)d_out;                // [16384,1024]

    char* ws = (char*)d_ws;
    unsigned short* hA  = (unsigned short*)(ws);                  // 64 MiB
    unsigned short* hB  = (unsigned short*)(ws + (67108864L));    // 64 MiB
    unsigned short* Wbf = (unsigned short*)(ws + (134217728L));   // 32 MiB
    unsigned short* Wlb = (unsigned short*)(ws + (167772160L));   // 4 MiB

    cvt_kernel<<<2048, 256, 0, stream>>>(Ws, Wbf, 4L * 2048 * 2048 / 4);
    cvt_kernel<<<512, 256, 0, stream>>>(Wl, Wlb, 1024L * 2048 / 4);

    attn_kernel<<<16384 / 4, 256, 0, stream>>>(x1, x2, hA);

    // MLP: 4x relu GEMM (bf16 ping-pong) + final GEMM (f32 out)
    gemm256<true, unsigned short><<<512, 512, 0, stream>>>(hA, Wbf + 0L * 2048 * 2048, bs + 0 * 2048, hB, 2048, 2048);
    gemm256<true, unsigned short><<<512, 512, 0, stream>>>(hB, Wbf + 1L * 2048 * 2048, bs + 1 * 2048, hA, 2048, 2048);
    gemm256<true, unsigned short><<<512, 512, 0, stream>>>(hA, Wbf + 2L * 2048 * 2048, bs + 2 * 2048, hB, 2048, 2048);
    gemm256<true, unsigned short><<<512, 512, 0, stream>>>(hB, Wbf + 3L * 2048 * 2048, bs + 3 * 2048, hA, 2048, 2048);
    gemm256<false, float><<<256, 512, 0, stream>>>(hA, Wlb, bl, out, 1024, 2048);
}

// Round 5
// 662.448 us; speedup vs baseline: 1.4515x; 1.0046x over previous
//
#include <hip/hip_runtime.h>

// ---------------- types ----------------
typedef __bf16 bf16x8 __attribute__((ext_vector_type(8)));
typedef float f32x4 __attribute__((ext_vector_type(4)));

__device__ __forceinline__ unsigned short f2bf(float f) {
    unsigned int u = __builtin_bit_cast(unsigned int, f);
    u += 0x7FFFu + ((u >> 16) & 1u);
    return (unsigned short)(u >> 16);
}

// ---------------- weight f32 -> bf16 conversion ----------------
__global__ void cvt_kernel(const float* __restrict__ in,
                           unsigned short* __restrict__ out, long n4) {
    long i = (long)blockIdx.x * blockDim.x + threadIdx.x;
    long stride = (long)gridDim.x * blockDim.x;
    for (; i < n4; i += stride) {
        float4 v = ((const float4*)in)[i];
        ushort4 o;
        o.x = f2bf(v.x); o.y = f2bf(v.y); o.z = f2bf(v.z); o.w = f2bf(v.w);
        ((ushort4*)out)[i] = o;
    }
}

// ---------------- fused 2-token attention -> h0 (bf16) ----------------
__global__ __launch_bounds__(256) void attn_kernel(
    const float* __restrict__ x1, const float* __restrict__ x2,
    unsigned short* __restrict__ h) {
    const int D = 1024;
    const int lane = threadIdx.x & 63;
    const int wave = threadIdx.x >> 6;
    const long row = (long)blockIdx.x * 4 + wave;
    const float4* p1 = (const float4*)(x1 + row * D);
    const float4* p2 = (const float4*)(x2 + row * D);
    float4 v1[4], v2[4];
    float s11 = 0.f, s12 = 0.f, s22 = 0.f;
#pragma unroll
    for (int j = 0; j < 4; ++j) {
        v1[j] = p1[lane + 64 * j];
        v2[j] = p2[lane + 64 * j];
        s11 += v1[j].x * v1[j].x + v1[j].y * v1[j].y + v1[j].z * v1[j].z + v1[j].w * v1[j].w;
        s12 += v1[j].x * v2[j].x + v1[j].y * v2[j].y + v1[j].z * v2[j].z + v1[j].w * v2[j].w;
        s22 += v2[j].x * v2[j].x + v2[j].y * v2[j].y + v2[j].z * v2[j].z + v2[j].w * v2[j].w;
    }
#pragma unroll
    for (int off = 1; off < 64; off <<= 1) {
        s11 += __shfl_xor(s11, off);
        s12 += __shfl_xor(s12, off);
        s22 += __shfl_xor(s22, off);
    }
    const float a00 = 1.f / (1.f + expf((s12 - s11) * (1.f / 32.f)));
    const float a10 = 1.f / (1.f + expf((s22 - s12) * (1.f / 32.f)));
    const float a01 = 1.f - a00, a11 = 1.f - a10;
    unsigned short* h0 = h + row * 2048;
#pragma unroll
    for (int j = 0; j < 4; ++j) {
        const int f = lane + 64 * j;
        ushort4 o0, o1;
        o0.x = f2bf(a00 * v1[j].x + a01 * v2[j].x);
        o0.y = f2bf(a00 * v1[j].y + a01 * v2[j].y);
        o0.z = f2bf(a00 * v1[j].z + a01 * v2[j].z);
        o0.w = f2bf(a00 * v1[j].w + a01 * v2[j].w);
        o1.x = f2bf(a10 * v1[j].x + a11 * v2[j].x);
        o1.y = f2bf(a10 * v1[j].y + a11 * v2[j].y);
        o1.z = f2bf(a10 * v1[j].z + a11 * v2[j].z);
        o1.w = f2bf(a10 * v1[j].w + a11 * v2[j].w);
        ((ushort4*)(h0))[f] = o0;
        ((ushort4*)(h0 + 1024))[f] = o1;
    }
}

// ---------------- 256x256 8-phase GEMM: C = act(A[M,K] * Bw[N,K]^T + bias) ----
// BM=BN=256, BK=64, 8 waves (2Mx4N), 128 KiB LDS = 2 K-tile dbuf.
// Phase clusters regrouped by kk: reads 8,8,8,0 per K-tile; stages placed so
// every vmcnt(4)-waited load is >=3 phases old. MFMA operands SWAPPED
// (mfma(Wfrag, ActFrag)) so lanes own 4 consecutive C-cols -> packed stores.
#define BAR   __builtin_amdgcn_s_barrier()
#define LGKM0 asm volatile("s_waitcnt lgkmcnt(0)" ::: "memory")
#define VMW(n) asm volatile("s_waitcnt vmcnt(" #n ")" ::: "memory")
#define PRIO1 __builtin_amdgcn_s_setprio(1)
#define PRIO0 __builtin_amdgcn_s_setprio(0)

#define MMQ(mb, kk)                                                            \
  _Pragma("unroll") for (int n = 0; n < 4; ++n)                                \
  _Pragma("unroll") for (int mq = 0; mq < 4; ++mq)                             \
    acc[(mb) + mq][n] = __builtin_amdgcn_mfma_f32_16x16x32_bf16(               \
        Bf[n][kk], Af[mq][kk], acc[(mb) + mq][n], 0, 0, 0);

template <bool RELU, typename OT>
__global__ __launch_bounds__(512, 2) void gemm256(
    const unsigned short* __restrict__ A,   // [M,K] bf16 (activations)
    const unsigned short* __restrict__ Bw,  // [N,K] bf16 (weights)
    const float* __restrict__ bias,         // [N]
    OT* __restrict__ C,                     // [M,N]
    int N, int K) {
    __shared__ __align__(16) unsigned short lds[65536];  // 128 KiB: T0|T1
    const int tid = threadIdx.x;
    const int lane = tid & 63, wave = tid >> 6;
    const int wm = wave >> 2, wn = wave & 3;
    const int fr = lane & 15, fq = lane >> 4;

    // XCD-swizzled 1D block id -> (bm, bn)
    const int cpx = (int)gridDim.x >> 3;
    const int swz = ((int)blockIdx.x & 7) * cpx + ((int)blockIdx.x >> 3);
    const int bm = swz & 63;
    const int bn = swz >> 6;
    const long m0 = (long)bm * 256, n0 = (long)bn * 256;

    // LDS read bases (byte offsets); kk=1 address = kk=0 address ^ 64.
    const int x0 = fq ^ (fr & 7);
    const int lane_base = fr * 128 + x0 * 16;
    const int aBase = wm * 16384 + lane_base;
    const int bBase = 32768 + (wn >> 1) * 16384 + (wn & 1) * 8192 + lane_base;
    const char* ldsc = (const char*)lds;

    // staging: per-lane pre-swizzled global source offset (same for A and B)
    const int l3 = lane >> 3, l7 = lane & 7;
    const long rowb = (long)K * 2;
    const long lane_src = (long)l3 * rowb + ((l7 ^ l3) << 4);
    const char* Abl = (const char*)A + m0 * rowb + lane_src;
    const char* Bbl = (const char*)Bw + n0 * rowb + lane_src;

    auto stage = [&](const char* mb, int matOff, int hf, int kt, int T) {
#pragma unroll
        for (int r = 0; r < 2; ++r) {
            const int W = r * 8 + wave;
            const char* src = mb + (long)(hf * 128 + W * 8) * rowb + kt * 128;
            __builtin_amdgcn_global_load_lds(
                (const __attribute__((address_space(1))) void*)src,
                (__attribute__((address_space(3))) void*)((char*)lds +
                    (T * 65536 + matOff + hf * 16384 + W * 1024)),
                16, 0, 0);
        }
    };

    f32x4 acc[8][4] = {};
    bf16x8 Bf[4][2], Af[4][2];

    auto readBA = [&](int boff, int kk) {   // Bf[.][kk] + Af(m0-3)[kk]: 8 reads
        const int x = kk * 64;
#pragma unroll
        for (int n = 0; n < 4; ++n)
            Bf[n][kk] = *(const bf16x8*)(ldsc + boff + (bBase ^ x) + n * 2048);
#pragma unroll
        for (int m = 0; m < 4; ++m)
            Af[m][kk] = *(const bf16x8*)(ldsc + boff + (aBase ^ x) + m * 2048);
    };
    auto readAH = [&](int boff) {           // Af <- m4-7, both kk: 8 reads
#pragma unroll
        for (int m = 0; m < 4; ++m) {
            Af[m][0] = *(const bf16x8*)(ldsc + boff + aBase + (m + 4) * 2048);
            Af[m][1] = *(const bf16x8*)(ldsc + boff + (aBase ^ 64) + (m + 4) * 2048);
        }
    };

    // ---- prologue: tile0 (A+B) -> T0; tile1 A halves -> T1 ----
    stage(Abl, 0,     0, 0, 0); stage(Abl, 0,     1, 0, 0);
    stage(Bbl, 32768, 0, 0, 0); stage(Bbl, 32768, 1, 0, 0);
    stage(Abl, 0,     0, 1, 1); stage(Abl, 0,     1, 1, 1);
    VMW(4);
    BAR;

    const int NT = K >> 6;       // K-tiles
    const int NIT = NT >> 1;     // iterations, 2 K-tiles each
    for (int i = 0; i < NIT; ++i) {
        const int t1 = 2 * i + 1, t2 = t1 + 1, t3 = t1 + 2;
        const bool g = (i + 1 < NIT);

        // ======== T0 half (tile 2i) ========
        // P1: read kk0 frags; stage B(t1)->T1 (T1 old reads drained at prev P7)
        readBA(0, 0);
        stage(Bbl, 32768, 0, t1, 1); stage(Bbl, 32768, 1, t1, 1);
        BAR; PRIO1; MMQ(0, 0); PRIO0; BAR;
        // P2: read kk1 frags (m0-3)
        readBA(0, 1);
        BAR; PRIO1; MMQ(0, 1); PRIO0; BAR;
        // P3: read m4-7 (both kk); full drain BEFORE barrier -> T0 free at P4
        readAH(0);
        LGKM0;
        BAR; PRIO1; MMQ(4, 0); PRIO0; BAR;
        // P4: stage A(t2)->T0; vmcnt(4) retires A(t1)+B(t1) (ages 4,3 phases)
        if (g) { stage(Abl, 0, 0, t2, 0); stage(Abl, 0, 1, t2, 0); }
        BAR; PRIO1; MMQ(4, 1); PRIO0;
        if (g) { VMW(4); } else { VMW(0); }
        BAR;

        // ======== T1 half (tile 2i+1) ========
        // P5: read kk0; stage B(t2)->T0
        readBA(65536, 0);
        if (g) { stage(Bbl, 32768, 0, t2, 0); stage(Bbl, 32768, 1, t2, 0); }
        BAR; PRIO1; MMQ(0, 0); PRIO0; BAR;
        // P6: read kk1 (m0-3)
        readBA(65536, 1);
        BAR; PRIO1; MMQ(0, 1); PRIO0; BAR;
        // P7: read m4-7; full drain -> T1 free at P8
        readAH(65536);
        LGKM0;
        BAR; PRIO1; MMQ(4, 0); PRIO0; BAR;
        // P8: stage A(t3)->T1; vmcnt(4) retires A(t2)+B(t2) (ages 4,3 phases)
        if (g) { stage(Abl, 0, 0, t3, 1); stage(Abl, 0, 1, t3, 1); }
        BAR; PRIO1; MMQ(4, 1); PRIO0;
        if (g) { VMW(4); } else { VMW(0); }
        BAR;
    }

    // ---- epilogue: swapped layout => lane owns row (fr) x 4 consecutive cols
    // crow = m0 + wm*128 + m*16 + fr ; ccol = n0 + wn*64 + n*16 + fq*4 + r
    const long crow0 = m0 + wm * 128 + fr;
    const long ccol0 = n0 + wn * 64 + fq * 4;
    float4 bv[4];
#pragma unroll
    for (int n = 0; n < 4; ++n) bv[n] = *(const float4*)(bias + ccol0 + n * 16);
#pragma unroll
    for (int m = 0; m < 8; ++m) {
        const long rb = (crow0 + m * 16) * N;
#pragma unroll
        for (int n = 0; n < 4; ++n) {
            float v0 = acc[m][n][0] + bv[n].x;
            float v1 = acc[m][n][1] + bv[n].y;
            float v2 = acc[m][n][2] + bv[n].z;
            float v3 = acc[m][n][3] + bv[n].w;
            if (RELU) {
                v0 = v0 > 0.f ? v0 : 0.f; v1 = v1 > 0.f ? v1 : 0.f;
                v2 = v2 > 0.f ? v2 : 0.f; v3 = v3 > 0.f ? v3 : 0.f;
            }
            if constexpr (sizeof(OT) == 2) {
                uint2 o;
                o.x = (unsigned)f2bf(v0) | ((unsigned)f2bf(v1) << 16);
                o.y = (unsigned)f2bf(v2) | ((unsigned)f2bf(v3) << 16);
                *(uint2*)((unsigned short*)C + rb + ccol0 + n * 16) = o;
            } else {
                *(float4*)((float*)C + rb + ccol0 + n * 16) =
                    make_float4(v0, v1, v2, v3);
            }
        }
    }
}

// ---------------- launch ----------------
extern "C" void kernel_launch(void* const* d_in, const int* in_sizes, int n_in,
                              void* d_out, int out_size, void* d_ws, size_t ws_size,
                              hipStream_t stream) {
    const float* x1 = (const float*)d_in[0];
    const float* x2 = (const float*)d_in[1];
    const float* Ws = (const float*)d_in[2];   // [4,2048,2048]
    const float* bs = (const float*)d_in[3];   // [4,2048]
    const float* Wl = (const float*)d_in[4];   // [1024,2048]
    const float* bl = (const float*)d_in[5];   // [1024]
    float* out = (float*)d_out;                // [16384,1024]

    char* ws = (char*)d_ws;
    unsigned short* hA  = (unsigned short*)(ws);                  // 64 MiB
    unsigned short* hB  = (unsigned short*)(ws + (67108864L));    // 64 MiB
    unsigned short* Wbf = (unsigned short*)(ws + (134217728L));   // 32 MiB
    unsigned short* Wlb = (unsigned short*)(ws + (167772160L));   // 4 MiB

    cvt_kernel<<<2048, 256, 0, stream>>>(Ws, Wbf, 4L * 2048 * 2048 / 4);
    cvt_kernel<<<512, 256, 0, stream>>>(Wl, Wlb, 1024L * 2048 / 4);

    attn_kernel<<<16384 / 4, 256, 0, stream>>>(x1, x2, hA);

    // MLP: 4x relu GEMM (bf16 ping-pong) + final GEMM (f32 out)
    gemm256<true, unsigned short><<<512, 512, 0, stream>>>(hA, Wbf + 0L * 2048 * 2048, bs + 0 * 2048, hB, 2048, 2048);
    gemm256<true, unsigned short><<<512, 512, 0, stream>>>(hB, Wbf + 1L * 2048 * 2048, bs + 1 * 2048, hA, 2048, 2048);
    gemm256<true, unsigned short><<<512, 512, 0, stream>>>(hA, Wbf + 2L * 2048 * 2048, bs + 2 * 2048, hB, 2048, 2048);
    gemm256<true, unsigned short><<<512, 512, 0, stream>>>(hB, Wbf + 3L * 2048 * 2048, bs + 3 * 2048, hA, 2048, 2048);
    gemm256<false, float><<<256, 512, 0, stream>>>(hA, Wlb, bl, out, 1024, 2048);
}